// Round 6
// baseline (1341.711 us; speedup 1.0000x reference)
//
#include <hip/hip_runtime.h>
#include <math.h>

#define N_NODES 50000
#define N_EDGES 800000
#define HID 128
#define H2 256
#define STEPS 12
#define DT 0.5f

#define SCAN_B 256
#define NB ((N_NODES + SCAN_B - 1) / SCAN_B)   // 196
#define H0_BLOCKS ((N_NODES + 31) / 32)        // 1563
#define MB 64
#define MLP_BLOCKS ((N_NODES + MB - 1) / MB)   // 782
#define N_PAD (MLP_BLOCKS * MB)                // 50048

typedef __attribute__((ext_vector_type(8))) short bf16x8;
typedef __attribute__((ext_vector_type(4))) float f32x4;

__device__ inline unsigned short f2bf(float x) {
    unsigned int u = __float_as_uint(x);
    unsigned int r = (u + 0x7FFFu + ((u >> 16) & 1u)) >> 16;  // round-nearest-even
    return (unsigned short)r;
}
__device__ inline float bf2f(unsigned short b) {
    return __uint_as_float(((unsigned int)b) << 16);
}
__device__ inline float u2f(unsigned int u) { return __uint_as_float(u); }

// ---------------- CSR build ----------------

__global__ void k_zero_counts(int* __restrict__ counts) {
    int i = blockIdx.x * 256 + threadIdx.x;
    if (i < N_NODES) counts[i] = 0;
}

__global__ void k_hist(const int* __restrict__ dst, int* __restrict__ counts) {
    int e = blockIdx.x * 256 + threadIdx.x;
    if (e < N_EDGES) atomicAdd(&counts[dst[e]], 1);
}

__global__ void k_blocksum(const int* __restrict__ counts, int* __restrict__ bsum) {
    __shared__ int s[SCAN_B];
    int idx = blockIdx.x * SCAN_B + threadIdx.x;
    int v = (idx < N_NODES) ? counts[idx] : 0;
    s[threadIdx.x] = v;
    __syncthreads();
    for (int off = SCAN_B / 2; off > 0; off >>= 1) {
        if (threadIdx.x < off) s[threadIdx.x] += s[threadIdx.x + off];
        __syncthreads();
    }
    if (threadIdx.x == 0) bsum[blockIdx.x] = s[0];
}

__global__ void k_scan_bsums(int* __restrict__ bsum, int* __restrict__ offsets) {
    if (threadIdx.x == 0 && blockIdx.x == 0) {
        int run = 0;
        for (int i = 0; i < NB; i++) { int t = bsum[i]; bsum[i] = run; run += t; }
        offsets[N_NODES] = N_EDGES;
    }
}

__global__ void k_offsets(const int* __restrict__ counts, const int* __restrict__ bsum,
                          int* __restrict__ offsets, int* __restrict__ cursor) {
    __shared__ int s[SCAN_B];
    int idx = blockIdx.x * SCAN_B + threadIdx.x;
    int v = (idx < N_NODES) ? counts[idx] : 0;
    s[threadIdx.x] = v;
    __syncthreads();
    for (int off = 1; off < SCAN_B; off <<= 1) {
        int t = 0;
        if ((int)threadIdx.x >= off) t = s[threadIdx.x - off];
        __syncthreads();
        s[threadIdx.x] += t;
        __syncthreads();
    }
    if (idx < N_NODES) {
        int excl = s[threadIdx.x] - v;
        int o = bsum[blockIdx.x] + excl;
        offsets[idx] = o;
        cursor[idx]  = o;
    }
}

__global__ void k_scatter(const int* __restrict__ src, const int* __restrict__ dst,
                          int* __restrict__ cursor, int* __restrict__ csr_src) {
    int e = blockIdx.x * 256 + threadIdx.x;
    if (e < N_EDGES) {
        int d = dst[e];
        int p = atomicAdd(&cursor[d], 1);
        csr_src[p] = src[e];
    }
}

// ---------------- weight pack: f32 [K][N] -> hi/lo bf16 in B-fragment order ----------------

__global__ void k_pack(const float* __restrict__ W, int K, int N,
                       unsigned short* __restrict__ hi, unsigned short* __restrict__ lo) {
    int KT = K >> 5, NT = N >> 4;
    int t = blockIdx.x * 256 + threadIdx.x;
    if (t >= KT * NT * 64) return;
    int l = t & 63, tile = t >> 6;
    int kt = tile % KT, nt = tile / KT;
    int n  = nt * 16 + (l & 15);
    int k0 = kt * 32 + (l >> 4) * 8;
    int base = ((nt * KT + kt) * 64 + l) * 8;
    for (int j = 0; j < 8; j++) {
        float w = W[(size_t)(k0 + j) * N + n];
        unsigned short h = f2bf(w);
        hi[base + j] = h;
        lo[base + j] = f2bf(w - bf2f(h));
    }
}

// ---------------- h0 = tanh(gat @ W_in + b_in), MFMA ----------------

__global__ __launch_bounds__(256, 3) void k_h0_mfma(
    const float* __restrict__ gat,
    const unsigned short* __restrict__ wh, const unsigned short* __restrict__ wl,
    const float* __restrict__ b_in, float* __restrict__ h,
    unsigned short* __restrict__ hbf) {
    __shared__ unsigned short Ahi[32][136];
    __shared__ unsigned short Alo[32][136];
    int tid = threadIdx.x;
    int node0 = blockIdx.x * 32;

    for (int idx = tid; idx < 32 * 64; idx += 256) {
        int m = idx >> 6, c = (idx & 63) * 2;
        float2 v;
        if (node0 + m < N_NODES) v = *(const float2*)&gat[(size_t)(node0 + m) * 128 + c];
        else { v.x = 0.f; v.y = 0.f; }
        unsigned short h0 = f2bf(v.x), h1 = f2bf(v.y);
        unsigned short l0 = f2bf(v.x - bf2f(h0)), l1 = f2bf(v.y - bf2f(h1));
        *(unsigned int*)&Ahi[m][c] = (unsigned int)h0 | ((unsigned int)h1 << 16);
        *(unsigned int*)&Alo[m][c] = (unsigned int)l0 | ((unsigned int)l1 << 16);
    }
    __syncthreads();

    int l = tid & 63, wv = tid >> 6;
    int c15 = l & 15, q = l >> 4;
    f32x4 acc[2][2] = {};
#pragma unroll
    for (int kt = 0; kt < 4; kt++) {
        bf16x8 ah[2], al[2];
#pragma unroll
        for (int mt = 0; mt < 2; mt++) {
            ah[mt] = *(const bf16x8*)&Ahi[mt * 16 + c15][kt * 32 + q * 8];
            al[mt] = *(const bf16x8*)&Alo[mt * 16 + c15][kt * 32 + q * 8];
        }
#pragma unroll
        for (int nn = 0; nn < 2; nn++) {
            int nt = wv * 2 + nn;
            bf16x8 bh = *(const bf16x8*)&wh[(size_t)((nt * 4 + kt) * 64 + l) * 8];
            bf16x8 bl = *(const bf16x8*)&wl[(size_t)((nt * 4 + kt) * 64 + l) * 8];
#pragma unroll
            for (int mt = 0; mt < 2; mt++) {
                acc[mt][nn] = __builtin_amdgcn_mfma_f32_16x16x32_bf16(ah[mt], bh, acc[mt][nn], 0, 0, 0);
                acc[mt][nn] = __builtin_amdgcn_mfma_f32_16x16x32_bf16(ah[mt], bl, acc[mt][nn], 0, 0, 0);
                acc[mt][nn] = __builtin_amdgcn_mfma_f32_16x16x32_bf16(al[mt], bh, acc[mt][nn], 0, 0, 0);
            }
        }
    }
#pragma unroll
    for (int nn = 0; nn < 2; nn++) {
        int col = (wv * 2 + nn) * 16 + c15;
        float bb = b_in[col];
#pragma unroll
        for (int mt = 0; mt < 2; mt++)
#pragma unroll
            for (int r = 0; r < 4; r++) {
                int node = node0 + mt * 16 + q * 4 + r;
                if (node < N_NODES) {
                    float v = tanhf(acc[mt][nn][r] + bb);
                    h[(size_t)node * 128 + col]   = v;
                    hbf[(size_t)node * 128 + col] = f2bf(v);
                }
            }
    }
}

// ---------------- gather: agg = segment_mean(hbf[src], dst), hi/lo bf16 planes ----------------

__global__ __launch_bounds__(256, 6) void k_gather(
    const unsigned short* __restrict__ hbf,
    const int* __restrict__ offsets, const int* __restrict__ csr,
    unsigned short* __restrict__ aggh, unsigned short* __restrict__ aggl) {
    int wv = threadIdx.x >> 6, l = threadIdx.x & 63;
    int node = blockIdx.x * 4 + wv;
    if (node >= N_NODES) return;
    int g = l >> 4;        // edge-group 0..3
    int cl = l & 15;       // col chunk: cols cl*8 .. +8
    int beg = offsets[node], end = offsets[node + 1];

    float a0 = 0.f, a1 = 0.f, a2 = 0.f, a3 = 0.f;
    float a4 = 0.f, a5 = 0.f, a6 = 0.f, a7 = 0.f;

    int e = beg + g;
    for (; e + 12 < end; e += 16) {
        int i0 = csr[e], i1 = csr[e + 4], i2 = csr[e + 8], i3 = csr[e + 12];
        uint4 w0 = *(const uint4*)&hbf[(size_t)i0 * 128 + cl * 8];
        uint4 w1 = *(const uint4*)&hbf[(size_t)i1 * 128 + cl * 8];
        uint4 w2 = *(const uint4*)&hbf[(size_t)i2 * 128 + cl * 8];
        uint4 w3 = *(const uint4*)&hbf[(size_t)i3 * 128 + cl * 8];
        a0 += u2f(w0.x << 16); a1 += u2f(w0.x & 0xFFFF0000u);
        a2 += u2f(w0.y << 16); a3 += u2f(w0.y & 0xFFFF0000u);
        a4 += u2f(w0.z << 16); a5 += u2f(w0.z & 0xFFFF0000u);
        a6 += u2f(w0.w << 16); a7 += u2f(w0.w & 0xFFFF0000u);
        a0 += u2f(w1.x << 16); a1 += u2f(w1.x & 0xFFFF0000u);
        a2 += u2f(w1.y << 16); a3 += u2f(w1.y & 0xFFFF0000u);
        a4 += u2f(w1.z << 16); a5 += u2f(w1.z & 0xFFFF0000u);
        a6 += u2f(w1.w << 16); a7 += u2f(w1.w & 0xFFFF0000u);
        a0 += u2f(w2.x << 16); a1 += u2f(w2.x & 0xFFFF0000u);
        a2 += u2f(w2.y << 16); a3 += u2f(w2.y & 0xFFFF0000u);
        a4 += u2f(w2.z << 16); a5 += u2f(w2.z & 0xFFFF0000u);
        a6 += u2f(w2.w << 16); a7 += u2f(w2.w & 0xFFFF0000u);
        a0 += u2f(w3.x << 16); a1 += u2f(w3.x & 0xFFFF0000u);
        a2 += u2f(w3.y << 16); a3 += u2f(w3.y & 0xFFFF0000u);
        a4 += u2f(w3.z << 16); a5 += u2f(w3.z & 0xFFFF0000u);
        a6 += u2f(w3.w << 16); a7 += u2f(w3.w & 0xFFFF0000u);
    }
    for (; e < end; e += 4) {
        int i0 = csr[e];
        uint4 w0 = *(const uint4*)&hbf[(size_t)i0 * 128 + cl * 8];
        a0 += u2f(w0.x << 16); a1 += u2f(w0.x & 0xFFFF0000u);
        a2 += u2f(w0.y << 16); a3 += u2f(w0.y & 0xFFFF0000u);
        a4 += u2f(w0.z << 16); a5 += u2f(w0.z & 0xFFFF0000u);
        a6 += u2f(w0.w << 16); a7 += u2f(w0.w & 0xFFFF0000u);
    }

    a0 += __shfl_xor(a0, 16); a1 += __shfl_xor(a1, 16);
    a2 += __shfl_xor(a2, 16); a3 += __shfl_xor(a3, 16);
    a4 += __shfl_xor(a4, 16); a5 += __shfl_xor(a5, 16);
    a6 += __shfl_xor(a6, 16); a7 += __shfl_xor(a7, 16);
    a0 += __shfl_xor(a0, 32); a1 += __shfl_xor(a1, 32);
    a2 += __shfl_xor(a2, 32); a3 += __shfl_xor(a3, 32);
    a4 += __shfl_xor(a4, 32); a5 += __shfl_xor(a5, 32);
    a6 += __shfl_xor(a6, 32); a7 += __shfl_xor(a7, 32);

    int deg = end - beg;
    float inv = (deg > 1) ? 1.0f / (float)deg : 1.0f;
    float x0 = a0 * inv, x1 = a1 * inv, x2 = a2 * inv, x3 = a3 * inv;
    float x4 = a4 * inv, x5 = a5 * inv, x6 = a6 * inv, x7 = a7 * inv;

    unsigned short h0 = f2bf(x0), h1 = f2bf(x1), h2 = f2bf(x2), h3 = f2bf(x3);
    unsigned short h4 = f2bf(x4), h5 = f2bf(x5), h6 = f2bf(x6), h7 = f2bf(x7);
    if (g == 0) {
        uint4 o;
        o.x = (unsigned int)h0 | ((unsigned int)h1 << 16);
        o.y = (unsigned int)h2 | ((unsigned int)h3 << 16);
        o.z = (unsigned int)h4 | ((unsigned int)h5 << 16);
        o.w = (unsigned int)h6 | ((unsigned int)h7 << 16);
        *(uint4*)&aggh[(size_t)node * 128 + cl * 8] = o;
    } else if (g == 1) {
        unsigned short l0 = f2bf(x0 - bf2f(h0)), l1 = f2bf(x1 - bf2f(h1));
        unsigned short l2 = f2bf(x2 - bf2f(h2)), l3 = f2bf(x3 - bf2f(h3));
        unsigned short l4 = f2bf(x4 - bf2f(h4)), l5 = f2bf(x5 - bf2f(h5));
        unsigned short l6 = f2bf(x6 - bf2f(h6)), l7 = f2bf(x7 - bf2f(h7));
        uint4 o;
        o.x = (unsigned int)l0 | ((unsigned int)l1 << 16);
        o.y = (unsigned int)l2 | ((unsigned int)l3 << 16);
        o.z = (unsigned int)l4 | ((unsigned int)l5 << 16);
        o.w = (unsigned int)l6 | ((unsigned int)l7 << 16);
        *(uint4*)&aggl[(size_t)node * 128 + cl * 8] = o;
    }
}

// ---------------- fused MLP + Euler, M=64 tile, fat waves ----------------
// launch_bounds(256,2): VGPR cap 256. All 32 A-fragments prefetched in one
// burst (128 VGPRs in flight) -> high memory-level parallelism; weights
// streamed per-kt. Round-5 post-mortem: at 52 VGPR the wave serializes
// ~80 global loads in batches of ~4 against 200-400cy L2 latency.

__global__ __launch_bounds__(256, 2) void k_mlp(
    const unsigned short* __restrict__ aggh, const unsigned short* __restrict__ aggl,
    float* __restrict__ h, unsigned short* __restrict__ hbf,
    const unsigned short* __restrict__ w1h, const unsigned short* __restrict__ w1l,
    const float* __restrict__ b1,
    const unsigned short* __restrict__ w2h, const unsigned short* __restrict__ w2l,
    const float* __restrict__ b2, const float* __restrict__ clr) {
    __shared__ unsigned short Y[64][264];
    int tid = threadIdx.x, l = tid & 63, wv = tid >> 6;
    int c15 = l & 15, q = l >> 4;
    int node0 = blockIdx.x * MB;

    // GEMM1 [64x128]@[128x256]
    {
        // prefetch ALL A-fragments (4 kt x 4 mt, hi+lo) — 32 loads in flight
        bf16x8 ah[4][4], al[4][4];
#pragma unroll
        for (int kt = 0; kt < 4; kt++)
#pragma unroll
            for (int mt = 0; mt < 4; mt++) {
                size_t row = (size_t)(node0 + mt * 16 + c15);
                ah[kt][mt] = *(const bf16x8*)&aggh[row * 128 + kt * 32 + q * 8];
                al[kt][mt] = *(const bf16x8*)&aggl[row * 128 + kt * 32 + q * 8];
            }
        f32x4 acc1[4][4] = {};   // [mt][nn]
#pragma unroll
        for (int kt = 0; kt < 4; kt++) {
#pragma unroll
            for (int nn = 0; nn < 4; nn++) {
                int nt = wv * 4 + nn;
                bf16x8 bh = *(const bf16x8*)&w1h[(size_t)((nt * 4 + kt) * 64 + l) * 8];
                bf16x8 bl = *(const bf16x8*)&w1l[(size_t)((nt * 4 + kt) * 64 + l) * 8];
#pragma unroll
                for (int mt = 0; mt < 4; mt++) {
                    acc1[mt][nn] = __builtin_amdgcn_mfma_f32_16x16x32_bf16(ah[kt][mt], bh, acc1[mt][nn], 0, 0, 0);
                    acc1[mt][nn] = __builtin_amdgcn_mfma_f32_16x16x32_bf16(ah[kt][mt], bl, acc1[mt][nn], 0, 0, 0);
                    acc1[mt][nn] = __builtin_amdgcn_mfma_f32_16x16x32_bf16(al[kt][mt], bh, acc1[mt][nn], 0, 0, 0);
                }
            }
        }
        // epilogue: bias + exact gelu -> Y (bf16)
#pragma unroll
        for (int nn = 0; nn < 4; nn++) {
            int col = (wv * 4 + nn) * 16 + c15;
            float bb = b1[col];
#pragma unroll
            for (int mt = 0; mt < 4; mt++)
#pragma unroll
                for (int r = 0; r < 4; r++) {
                    int row = mt * 16 + q * 4 + r;
                    float x = acc1[mt][nn][r] + bb;
                    float g = 0.5f * x * (1.0f + erff(x * 0.70710678118654752f));
                    Y[row][col] = f2bf(g);
                }
        }
    }
    __syncthreads();

    // GEMM2 [64x256]@[256x128], 2-product
    f32x4 acc2[4][2] = {};   // [mt][nn]
#pragma unroll
    for (int kt = 0; kt < 8; kt++) {
        bf16x8 ya[4];
#pragma unroll
        for (int mt = 0; mt < 4; mt++)
            ya[mt] = *(const bf16x8*)&Y[mt * 16 + c15][kt * 32 + q * 8];
#pragma unroll
        for (int nn = 0; nn < 2; nn++) {
            int nt = wv * 2 + nn;
            bf16x8 bh = *(const bf16x8*)&w2h[(size_t)((nt * 8 + kt) * 64 + l) * 8];
            bf16x8 bl = *(const bf16x8*)&w2l[(size_t)((nt * 8 + kt) * 64 + l) * 8];
#pragma unroll
            for (int mt = 0; mt < 4; mt++) {
                acc2[mt][nn] = __builtin_amdgcn_mfma_f32_16x16x32_bf16(ya[mt], bh, acc2[mt][nn], 0, 0, 0);
                acc2[mt][nn] = __builtin_amdgcn_mfma_f32_16x16x32_bf16(ya[mt], bl, acc2[mt][nn], 0, 0, 0);
            }
        }
    }
    // epilogue: bias + tanh + Euler update (in place)
    float decay = fmaxf(clr[0], 0.0f);
#pragma unroll
    for (int nn = 0; nn < 2; nn++) {
        int col = (wv * 2 + nn) * 16 + c15;
        float bb = b2[col];
#pragma unroll
        for (int mt = 0; mt < 4; mt++)
#pragma unroll
            for (int r = 0; r < 4; r++) {
                int node = node0 + mt * 16 + q * 4 + r;
                if (node < N_NODES) {
                    float hv = h[(size_t)node * 128 + col];
                    float diff = tanhf(acc2[mt][nn][r] + bb);
                    float nh = hv + (diff - decay * hv) * DT;
                    h[(size_t)node * 128 + col]   = nh;
                    hbf[(size_t)node * 128 + col] = f2bf(nh);
                }
            }
    }
}

// ---------------- launch ----------------

extern "C" void kernel_launch(void* const* d_in, const int* in_sizes, int n_in,
                              void* d_out, int out_size, void* d_ws, size_t ws_size,
                              hipStream_t stream) {
    const float* gat   = (const float*)d_in[0];
    const int*   edges = (const int*)d_in[1];     // [2, E]: row0 = src, row1 = dst
    const float* W_in  = (const float*)d_in[2];
    const float* b_in  = (const float*)d_in[3];
    const float* W1    = (const float*)d_in[4];
    const float* b1    = (const float*)d_in[5];
    const float* W2    = (const float*)d_in[6];
    const float* b2    = (const float*)d_in[7];
    const float* clr   = (const float*)d_in[8];
    float* h = (float*)d_out;

    const int* src = edges;
    const int* dst = edges + N_EDGES;

    char* ws = (char*)d_ws;
    size_t off = 0;
    auto alloc = [&](size_t bytes) -> void* {
        off = (off + 255) & ~(size_t)255;
        void* p = ws + off;
        off += bytes;
        return p;
    };
    int*   counts  = (int*)alloc(sizeof(int) * N_NODES);
    int*   offsets = (int*)alloc(sizeof(int) * (N_NODES + 1));
    int*   cursor  = (int*)alloc(sizeof(int) * N_NODES);
    int*   bsum    = (int*)alloc(sizeof(int) * NB);
    int*   csr_src = (int*)alloc(sizeof(int) * N_EDGES);
    unsigned short* hbf  = (unsigned short*)alloc(sizeof(short) * (size_t)N_PAD * HID);
    unsigned short* aggh = (unsigned short*)alloc(sizeof(short) * (size_t)N_PAD * HID);
    unsigned short* aggl = (unsigned short*)alloc(sizeof(short) * (size_t)N_PAD * HID);
    unsigned short* w1h  = (unsigned short*)alloc(sizeof(short) * HID * H2);
    unsigned short* w1l  = (unsigned short*)alloc(sizeof(short) * HID * H2);
    unsigned short* w2h  = (unsigned short*)alloc(sizeof(short) * H2 * HID);
    unsigned short* w2l  = (unsigned short*)alloc(sizeof(short) * H2 * HID);
    unsigned short* winh = (unsigned short*)alloc(sizeof(short) * HID * HID);
    unsigned short* winl = (unsigned short*)alloc(sizeof(short) * HID * HID);

    // weight packing (once per call)
    k_pack<<<16, 256, 0, stream>>>(W1, 128, 256, w1h, w1l);
    k_pack<<<16, 256, 0, stream>>>(W2, 256, 128, w2h, w2l);
    k_pack<<<8, 256, 0, stream>>>(W_in, 128, 128, winh, winl);

    // CSR build
    k_zero_counts<<<NB, 256, 0, stream>>>(counts);
    k_hist<<<(N_EDGES + 255) / 256, 256, 0, stream>>>(dst, counts);
    k_blocksum<<<NB, 256, 0, stream>>>(counts, bsum);
    k_scan_bsums<<<1, 64, 0, stream>>>(bsum, offsets);
    k_offsets<<<NB, 256, 0, stream>>>(counts, bsum, offsets, cursor);
    k_scatter<<<(N_EDGES + 255) / 256, 256, 0, stream>>>(src, dst, cursor, csr_src);

    // h0 (writes f32 h and bf16 hbf)
    k_h0_mfma<<<H0_BLOCKS, 256, 0, stream>>>(gat, winh, winl, b_in, h, hbf);

    // 12 Euler steps
    for (int s = 0; s < STEPS; s++) {
        k_gather<<<(N_NODES + 3) / 4, 256, 0, stream>>>(hbf, offsets, csr_src, aggh, aggl);
        k_mlp<<<MLP_BLOCKS, 256, 0, stream>>>(aggh, aggl, h, hbf,
                                              w1h, w1l, b1, w2h, w2l, b2, clr);
    }
}

// Round 7
// 1164.778 us; speedup vs baseline: 1.1519x; 1.1519x over previous
//
#include <hip/hip_runtime.h>
#include <math.h>

#define N_NODES 50000
#define N_EDGES 800000
#define HID 128
#define H2 256
#define STEPS 12
#define DT 0.5f

#define SCAN_B 256
#define NB ((N_NODES + SCAN_B - 1) / SCAN_B)   // 196
#define NODE_BLOCKS ((N_NODES + 31) / 32)      // 1563
#define N_PAD (NODE_BLOCKS * 32)               // 50016

typedef __attribute__((ext_vector_type(8))) short bf16x8;
typedef __attribute__((ext_vector_type(4))) float f32x4;

__device__ inline unsigned short f2bf(float x) {
    unsigned int u = __float_as_uint(x);
    unsigned int r = (u + 0x7FFFu + ((u >> 16) & 1u)) >> 16;  // round-nearest-even
    return (unsigned short)r;
}
__device__ inline float bf2f(unsigned short b) {
    return __uint_as_float(((unsigned int)b) << 16);
}
__device__ inline float u2f(unsigned int u) { return __uint_as_float(u); }

// ---------------- CSR build ----------------

__global__ void k_zero_counts(int* __restrict__ counts) {
    int i = blockIdx.x * 256 + threadIdx.x;
    if (i < N_NODES) counts[i] = 0;
}

__global__ void k_hist(const int* __restrict__ dst, int* __restrict__ counts) {
    int e = blockIdx.x * 256 + threadIdx.x;
    if (e < N_EDGES) atomicAdd(&counts[dst[e]], 1);
}

__global__ void k_blocksum(const int* __restrict__ counts, int* __restrict__ bsum) {
    __shared__ int s[SCAN_B];
    int idx = blockIdx.x * SCAN_B + threadIdx.x;
    int v = (idx < N_NODES) ? counts[idx] : 0;
    s[threadIdx.x] = v;
    __syncthreads();
    for (int off = SCAN_B / 2; off > 0; off >>= 1) {
        if (threadIdx.x < off) s[threadIdx.x] += s[threadIdx.x + off];
        __syncthreads();
    }
    if (threadIdx.x == 0) bsum[blockIdx.x] = s[0];
}

__global__ void k_scan_bsums(int* __restrict__ bsum, int* __restrict__ offsets) {
    if (threadIdx.x == 0 && blockIdx.x == 0) {
        int run = 0;
        for (int i = 0; i < NB; i++) { int t = bsum[i]; bsum[i] = run; run += t; }
        offsets[N_NODES] = N_EDGES;
    }
}

__global__ void k_offsets(const int* __restrict__ counts, const int* __restrict__ bsum,
                          int* __restrict__ offsets, int* __restrict__ cursor) {
    __shared__ int s[SCAN_B];
    int idx = blockIdx.x * SCAN_B + threadIdx.x;
    int v = (idx < N_NODES) ? counts[idx] : 0;
    s[threadIdx.x] = v;
    __syncthreads();
    for (int off = 1; off < SCAN_B; off <<= 1) {
        int t = 0;
        if ((int)threadIdx.x >= off) t = s[threadIdx.x - off];
        __syncthreads();
        s[threadIdx.x] += t;
        __syncthreads();
    }
    if (idx < N_NODES) {
        int excl = s[threadIdx.x] - v;
        int o = bsum[blockIdx.x] + excl;
        offsets[idx] = o;
        cursor[idx]  = o;
    }
}

__global__ void k_scatter(const int* __restrict__ src, const int* __restrict__ dst,
                          int* __restrict__ cursor, int* __restrict__ csr_src) {
    int e = blockIdx.x * 256 + threadIdx.x;
    if (e < N_EDGES) {
        int d = dst[e];
        int p = atomicAdd(&cursor[d], 1);
        csr_src[p] = src[e];
    }
}

// ---------------- weight pack: f32 [K][N] -> hi/lo bf16 in B-fragment order ----------------

__global__ void k_pack(const float* __restrict__ W, int K, int N,
                       unsigned short* __restrict__ hi, unsigned short* __restrict__ lo) {
    int KT = K >> 5, NT = N >> 4;
    int t = blockIdx.x * 256 + threadIdx.x;
    if (t >= KT * NT * 64) return;
    int l = t & 63, tile = t >> 6;
    int kt = tile % KT, nt = tile / KT;
    int n  = nt * 16 + (l & 15);
    int k0 = kt * 32 + (l >> 4) * 8;
    int base = ((nt * KT + kt) * 64 + l) * 8;
    for (int j = 0; j < 8; j++) {
        float w = W[(size_t)(k0 + j) * N + n];
        unsigned short h = f2bf(w);
        hi[base + j] = h;
        lo[base + j] = f2bf(w - bf2f(h));
    }
}

// ---------------- h0 = tanh(gat @ W_in + b_in), MFMA ----------------

__global__ __launch_bounds__(256, 3) void k_h0_mfma(
    const float* __restrict__ gat,
    const unsigned short* __restrict__ wh, const unsigned short* __restrict__ wl,
    const float* __restrict__ b_in, float* __restrict__ h,
    unsigned short* __restrict__ hbf) {
    __shared__ unsigned short Ahi[32][136];
    __shared__ unsigned short Alo[32][136];
    int tid = threadIdx.x;
    int node0 = blockIdx.x * 32;

    for (int idx = tid; idx < 32 * 64; idx += 256) {
        int m = idx >> 6, c = (idx & 63) * 2;
        float2 v;
        if (node0 + m < N_NODES) v = *(const float2*)&gat[(size_t)(node0 + m) * 128 + c];
        else { v.x = 0.f; v.y = 0.f; }
        unsigned short h0 = f2bf(v.x), h1 = f2bf(v.y);
        unsigned short l0 = f2bf(v.x - bf2f(h0)), l1 = f2bf(v.y - bf2f(h1));
        *(unsigned int*)&Ahi[m][c] = (unsigned int)h0 | ((unsigned int)h1 << 16);
        *(unsigned int*)&Alo[m][c] = (unsigned int)l0 | ((unsigned int)l1 << 16);
    }
    __syncthreads();

    int l = tid & 63, wv = tid >> 6;
    int c15 = l & 15, q = l >> 4;
    f32x4 acc[2][2] = {};
#pragma unroll
    for (int kt = 0; kt < 4; kt++) {
        bf16x8 ah[2], al[2];
#pragma unroll
        for (int mt = 0; mt < 2; mt++) {
            ah[mt] = *(const bf16x8*)&Ahi[mt * 16 + c15][kt * 32 + q * 8];
            al[mt] = *(const bf16x8*)&Alo[mt * 16 + c15][kt * 32 + q * 8];
        }
#pragma unroll
        for (int nn = 0; nn < 2; nn++) {
            int nt = wv * 2 + nn;
            bf16x8 bh = *(const bf16x8*)&wh[(size_t)((nt * 4 + kt) * 64 + l) * 8];
            bf16x8 bl = *(const bf16x8*)&wl[(size_t)((nt * 4 + kt) * 64 + l) * 8];
#pragma unroll
            for (int mt = 0; mt < 2; mt++) {
                acc[mt][nn] = __builtin_amdgcn_mfma_f32_16x16x32_bf16(ah[mt], bh, acc[mt][nn], 0, 0, 0);
                acc[mt][nn] = __builtin_amdgcn_mfma_f32_16x16x32_bf16(ah[mt], bl, acc[mt][nn], 0, 0, 0);
                acc[mt][nn] = __builtin_amdgcn_mfma_f32_16x16x32_bf16(al[mt], bh, acc[mt][nn], 0, 0, 0);
            }
        }
    }
#pragma unroll
    for (int nn = 0; nn < 2; nn++) {
        int col = (wv * 2 + nn) * 16 + c15;
        float bb = b_in[col];
#pragma unroll
        for (int mt = 0; mt < 2; mt++)
#pragma unroll
            for (int r = 0; r < 4; r++) {
                int node = node0 + mt * 16 + q * 4 + r;
                if (node < N_NODES) {
                    float v = tanhf(acc[mt][nn][r] + bb);
                    h[(size_t)node * 128 + col]   = v;
                    hbf[(size_t)node * 128 + col] = f2bf(v);
                }
            }
    }
}

// ---------------- fused step: gather -> LDS -> GEMM1+gelu -> GEMM2+tanh -> Euler ----------------
// Phase 1 (per wave, 8 nodes serial): bf16 uint4 gather, 16 lanes x 8 cols,
//   4 edge groups, unroll 4 -> hi/lo split written straight to Ahi/Alo LDS.
// Phase 2: GEMM1 3-product (A from LDS), gelu -> Y bf16.
// Phase 3: GEMM2 2-product, tanh, Euler in-place on f32 h; bf16 state ping-pongs.
// LDS 33.9 KB -> 4 blocks/CU; launch_bounds(256,4) = round-5-proven VGPR budget.

__global__ __launch_bounds__(256, 4) void k_step(
    const unsigned short* __restrict__ hbf_in,
    float* __restrict__ h, unsigned short* __restrict__ hbf_out,
    const int* __restrict__ offsets, const int* __restrict__ csr,
    const unsigned short* __restrict__ w1h, const unsigned short* __restrict__ w1l,
    const float* __restrict__ b1,
    const unsigned short* __restrict__ w2h, const unsigned short* __restrict__ w2l,
    const float* __restrict__ b2, const float* __restrict__ clr) {
    __shared__ unsigned short Ahi[32][136];
    __shared__ unsigned short Alo[32][136];
    __shared__ unsigned short Y[32][264];
    int tid = threadIdx.x, l = tid & 63, wv = tid >> 6;
    int c15 = l & 15, q = l >> 4;
    int node0 = blockIdx.x * 32;
    int g  = l >> 4;       // edge group 0..3
    int cl = l & 15;       // col chunk: cols cl*8..+8

    // ---- Phase 1: segment-mean gather into LDS hi/lo planes ----
#pragma unroll 1
    for (int i = 0; i < 8; i++) {
        int m = wv * 8 + i;
        int node = node0 + m;
        float a0 = 0.f, a1 = 0.f, a2 = 0.f, a3 = 0.f;
        float a4 = 0.f, a5 = 0.f, a6 = 0.f, a7 = 0.f;
        int deg = 0;
        if (node < N_NODES) {
            int beg = offsets[node], end = offsets[node + 1];
            deg = end - beg;
            int e = beg + g;
            for (; e + 12 < end; e += 16) {
                int i0 = csr[e], i1 = csr[e + 4], i2 = csr[e + 8], i3 = csr[e + 12];
                uint4 w0 = *(const uint4*)&hbf_in[(size_t)i0 * 128 + cl * 8];
                uint4 w1 = *(const uint4*)&hbf_in[(size_t)i1 * 128 + cl * 8];
                uint4 w2 = *(const uint4*)&hbf_in[(size_t)i2 * 128 + cl * 8];
                uint4 w3 = *(const uint4*)&hbf_in[(size_t)i3 * 128 + cl * 8];
                a0 += u2f(w0.x << 16); a1 += u2f(w0.x & 0xFFFF0000u);
                a2 += u2f(w0.y << 16); a3 += u2f(w0.y & 0xFFFF0000u);
                a4 += u2f(w0.z << 16); a5 += u2f(w0.z & 0xFFFF0000u);
                a6 += u2f(w0.w << 16); a7 += u2f(w0.w & 0xFFFF0000u);
                a0 += u2f(w1.x << 16); a1 += u2f(w1.x & 0xFFFF0000u);
                a2 += u2f(w1.y << 16); a3 += u2f(w1.y & 0xFFFF0000u);
                a4 += u2f(w1.z << 16); a5 += u2f(w1.z & 0xFFFF0000u);
                a6 += u2f(w1.w << 16); a7 += u2f(w1.w & 0xFFFF0000u);
                a0 += u2f(w2.x << 16); a1 += u2f(w2.x & 0xFFFF0000u);
                a2 += u2f(w2.y << 16); a3 += u2f(w2.y & 0xFFFF0000u);
                a4 += u2f(w2.z << 16); a5 += u2f(w2.z & 0xFFFF0000u);
                a6 += u2f(w2.w << 16); a7 += u2f(w2.w & 0xFFFF0000u);
                a0 += u2f(w3.x << 16); a1 += u2f(w3.x & 0xFFFF0000u);
                a2 += u2f(w3.y << 16); a3 += u2f(w3.y & 0xFFFF0000u);
                a4 += u2f(w3.z << 16); a5 += u2f(w3.z & 0xFFFF0000u);
                a6 += u2f(w3.w << 16); a7 += u2f(w3.w & 0xFFFF0000u);
            }
            for (; e < end; e += 4) {
                int i0 = csr[e];
                uint4 w0 = *(const uint4*)&hbf_in[(size_t)i0 * 128 + cl * 8];
                a0 += u2f(w0.x << 16); a1 += u2f(w0.x & 0xFFFF0000u);
                a2 += u2f(w0.y << 16); a3 += u2f(w0.y & 0xFFFF0000u);
                a4 += u2f(w0.z << 16); a5 += u2f(w0.z & 0xFFFF0000u);
                a6 += u2f(w0.w << 16); a7 += u2f(w0.w & 0xFFFF0000u);
            }
        }
        // combine 4 edge groups
        a0 += __shfl_xor(a0, 16); a1 += __shfl_xor(a1, 16);
        a2 += __shfl_xor(a2, 16); a3 += __shfl_xor(a3, 16);
        a4 += __shfl_xor(a4, 16); a5 += __shfl_xor(a5, 16);
        a6 += __shfl_xor(a6, 16); a7 += __shfl_xor(a7, 16);
        a0 += __shfl_xor(a0, 32); a1 += __shfl_xor(a1, 32);
        a2 += __shfl_xor(a2, 32); a3 += __shfl_xor(a3, 32);
        a4 += __shfl_xor(a4, 32); a5 += __shfl_xor(a5, 32);
        a6 += __shfl_xor(a6, 32); a7 += __shfl_xor(a7, 32);

        float inv = (deg > 1) ? 1.0f / (float)deg : 1.0f;
        float x0 = a0 * inv, x1 = a1 * inv, x2 = a2 * inv, x3 = a3 * inv;
        float x4 = a4 * inv, x5 = a5 * inv, x6 = a6 * inv, x7 = a7 * inv;
        unsigned short h0 = f2bf(x0), h1 = f2bf(x1), h2 = f2bf(x2), h3 = f2bf(x3);
        unsigned short h4 = f2bf(x4), h5 = f2bf(x5), h6 = f2bf(x6), h7 = f2bf(x7);
        if (g == 0) {
            uint4 o;
            o.x = (unsigned int)h0 | ((unsigned int)h1 << 16);
            o.y = (unsigned int)h2 | ((unsigned int)h3 << 16);
            o.z = (unsigned int)h4 | ((unsigned int)h5 << 16);
            o.w = (unsigned int)h6 | ((unsigned int)h7 << 16);
            *(uint4*)&Ahi[m][cl * 8] = o;
        } else if (g == 1) {
            unsigned short l0 = f2bf(x0 - bf2f(h0)), l1 = f2bf(x1 - bf2f(h1));
            unsigned short l2 = f2bf(x2 - bf2f(h2)), l3 = f2bf(x3 - bf2f(h3));
            unsigned short l4 = f2bf(x4 - bf2f(h4)), l5 = f2bf(x5 - bf2f(h5));
            unsigned short l6 = f2bf(x6 - bf2f(h6)), l7 = f2bf(x7 - bf2f(h7));
            uint4 o;
            o.x = (unsigned int)l0 | ((unsigned int)l1 << 16);
            o.y = (unsigned int)l2 | ((unsigned int)l3 << 16);
            o.z = (unsigned int)l4 | ((unsigned int)l5 << 16);
            o.w = (unsigned int)l6 | ((unsigned int)l7 << 16);
            *(uint4*)&Alo[m][cl * 8] = o;
        }
    }
    __syncthreads();

    // ---- Phase 2: GEMM1 [32x128]@[128x256], 3-product, gelu -> Y ----
    {
        f32x4 acc1[2][4] = {};
#pragma unroll
        for (int kt = 0; kt < 4; kt++) {
            bf16x8 ah[2], al[2];
#pragma unroll
            for (int mt = 0; mt < 2; mt++) {
                ah[mt] = *(const bf16x8*)&Ahi[mt * 16 + c15][kt * 32 + q * 8];
                al[mt] = *(const bf16x8*)&Alo[mt * 16 + c15][kt * 32 + q * 8];
            }
#pragma unroll
            for (int nn = 0; nn < 4; nn++) {
                int nt = wv * 4 + nn;
                bf16x8 bh = *(const bf16x8*)&w1h[(size_t)((nt * 4 + kt) * 64 + l) * 8];
                bf16x8 bl = *(const bf16x8*)&w1l[(size_t)((nt * 4 + kt) * 64 + l) * 8];
#pragma unroll
                for (int mt = 0; mt < 2; mt++) {
                    acc1[mt][nn] = __builtin_amdgcn_mfma_f32_16x16x32_bf16(ah[mt], bh, acc1[mt][nn], 0, 0, 0);
                    acc1[mt][nn] = __builtin_amdgcn_mfma_f32_16x16x32_bf16(ah[mt], bl, acc1[mt][nn], 0, 0, 0);
                    acc1[mt][nn] = __builtin_amdgcn_mfma_f32_16x16x32_bf16(al[mt], bh, acc1[mt][nn], 0, 0, 0);
                }
            }
        }
#pragma unroll
        for (int nn = 0; nn < 4; nn++) {
            int col = (wv * 4 + nn) * 16 + c15;
            float bb = b1[col];
#pragma unroll
            for (int mt = 0; mt < 2; mt++)
#pragma unroll
                for (int r = 0; r < 4; r++) {
                    int row = mt * 16 + q * 4 + r;
                    float x = acc1[mt][nn][r] + bb;
                    float gg = 0.5f * x * (1.0f + erff(x * 0.70710678118654752f));
                    Y[row][col] = f2bf(gg);
                }
        }
    }
    __syncthreads();

    // ---- Phase 3: GEMM2 [32x256]@[256x128], 2-product, tanh, Euler ----
    f32x4 acc2[2][2] = {};
#pragma unroll
    for (int kt = 0; kt < 8; kt++) {
        bf16x8 ya[2];
#pragma unroll
        for (int mt = 0; mt < 2; mt++)
            ya[mt] = *(const bf16x8*)&Y[mt * 16 + c15][kt * 32 + q * 8];
#pragma unroll
        for (int nn = 0; nn < 2; nn++) {
            int nt = wv * 2 + nn;
            bf16x8 bh = *(const bf16x8*)&w2h[(size_t)((nt * 8 + kt) * 64 + l) * 8];
            bf16x8 bl = *(const bf16x8*)&w2l[(size_t)((nt * 8 + kt) * 64 + l) * 8];
#pragma unroll
            for (int mt = 0; mt < 2; mt++) {
                acc2[mt][nn] = __builtin_amdgcn_mfma_f32_16x16x32_bf16(ya[mt], bh, acc2[mt][nn], 0, 0, 0);
                acc2[mt][nn] = __builtin_amdgcn_mfma_f32_16x16x32_bf16(ya[mt], bl, acc2[mt][nn], 0, 0, 0);
            }
        }
    }
    float decay = fmaxf(clr[0], 0.0f);
#pragma unroll
    for (int nn = 0; nn < 2; nn++) {
        int col = (wv * 2 + nn) * 16 + c15;
        float bb = b2[col];
#pragma unroll
        for (int mt = 0; mt < 2; mt++)
#pragma unroll
            for (int r = 0; r < 4; r++) {
                int node = node0 + mt * 16 + q * 4 + r;
                if (node < N_NODES) {
                    float hv = h[(size_t)node * 128 + col];
                    float diff = tanhf(acc2[mt][nn][r] + bb);
                    float nh = hv + (diff - decay * hv) * DT;
                    h[(size_t)node * 128 + col]       = nh;
                    hbf_out[(size_t)node * 128 + col] = f2bf(nh);
                }
            }
    }
}

// ---------------- launch ----------------

extern "C" void kernel_launch(void* const* d_in, const int* in_sizes, int n_in,
                              void* d_out, int out_size, void* d_ws, size_t ws_size,
                              hipStream_t stream) {
    const float* gat   = (const float*)d_in[0];
    const int*   edges = (const int*)d_in[1];     // [2, E]: row0 = src, row1 = dst
    const float* W_in  = (const float*)d_in[2];
    const float* b_in  = (const float*)d_in[3];
    const float* W1    = (const float*)d_in[4];
    const float* b1    = (const float*)d_in[5];
    const float* W2    = (const float*)d_in[6];
    const float* b2    = (const float*)d_in[7];
    const float* clr   = (const float*)d_in[8];
    float* h = (float*)d_out;

    const int* src = edges;
    const int* dst = edges + N_EDGES;

    char* ws = (char*)d_ws;
    size_t off = 0;
    auto alloc = [&](size_t bytes) -> void* {
        off = (off + 255) & ~(size_t)255;
        void* p = ws + off;
        off += bytes;
        return p;
    };
    int*   counts  = (int*)alloc(sizeof(int) * N_NODES);
    int*   offsets = (int*)alloc(sizeof(int) * (N_NODES + 1));
    int*   cursor  = (int*)alloc(sizeof(int) * N_NODES);
    int*   bsum    = (int*)alloc(sizeof(int) * NB);
    int*   csr_src = (int*)alloc(sizeof(int) * N_EDGES);
    unsigned short* hbfA = (unsigned short*)alloc(sizeof(short) * (size_t)N_PAD * HID);
    unsigned short* hbfB = (unsigned short*)alloc(sizeof(short) * (size_t)N_PAD * HID);
    unsigned short* w1h  = (unsigned short*)alloc(sizeof(short) * HID * H2);
    unsigned short* w1l  = (unsigned short*)alloc(sizeof(short) * HID * H2);
    unsigned short* w2h  = (unsigned short*)alloc(sizeof(short) * H2 * HID);
    unsigned short* w2l  = (unsigned short*)alloc(sizeof(short) * H2 * HID);
    unsigned short* winh = (unsigned short*)alloc(sizeof(short) * HID * HID);
    unsigned short* winl = (unsigned short*)alloc(sizeof(short) * HID * HID);

    // weight packing (once per call)
    k_pack<<<16, 256, 0, stream>>>(W1, 128, 256, w1h, w1l);
    k_pack<<<16, 256, 0, stream>>>(W2, 256, 128, w2h, w2l);
    k_pack<<<8, 256, 0, stream>>>(W_in, 128, 128, winh, winl);

    // CSR build
    k_zero_counts<<<NB, 256, 0, stream>>>(counts);
    k_hist<<<(N_EDGES + 255) / 256, 256, 0, stream>>>(dst, counts);
    k_blocksum<<<NB, 256, 0, stream>>>(counts, bsum);
    k_scan_bsums<<<1, 64, 0, stream>>>(bsum, offsets);
    k_offsets<<<NB, 256, 0, stream>>>(counts, bsum, offsets, cursor);
    k_scatter<<<(N_EDGES + 255) / 256, 256, 0, stream>>>(src, dst, cursor, csr_src);

    // h0 (writes f32 h and bf16 hbfA)
    k_h0_mfma<<<NODE_BLOCKS, 256, 0, stream>>>(gat, winh, winl, b_in, h, hbfA);

    // 12 fused Euler steps; bf16 state ping-pongs, f32 h in place
    for (int s = 0; s < STEPS; s++) {
        const unsigned short* in = (s & 1) ? hbfB : hbfA;
        unsigned short*      out = (s & 1) ? hbfA : hbfB;
        k_step<<<NODE_BLOCKS, 256, 0, stream>>>(in, h, out, offsets, csr_src,
                                                w1h, w1l, b1, w2h, w2l, b2, clr);
    }
}

// Round 8
// 891.332 us; speedup vs baseline: 1.5053x; 1.3068x over previous
//
#include <hip/hip_runtime.h>
#include <math.h>

#define N_NODES 50000
#define N_EDGES 800000
#define HID 128
#define H2 256
#define STEPS 12
#define DT 0.5f

#define SCAN_B 256
#define NB ((N_NODES + SCAN_B - 1) / SCAN_B)   // 196
#define NODE_BLOCKS ((N_NODES + 31) / 32)      // 1563
#define N_PAD (NODE_BLOCKS * 32)               // 50016

typedef __attribute__((ext_vector_type(8))) short bf16x8;
typedef __attribute__((ext_vector_type(4))) float f32x4;

__device__ inline unsigned short f2bf(float x) {
    unsigned int u = __float_as_uint(x);
    unsigned int r = (u + 0x7FFFu + ((u >> 16) & 1u)) >> 16;  // round-nearest-even
    return (unsigned short)r;
}
__device__ inline float bf2f(unsigned short b) {
    return __uint_as_float(((unsigned int)b) << 16);
}
__device__ inline float u2f(unsigned int u) { return __uint_as_float(u); }

// ---------------- CSR build ----------------

__global__ void k_zero_counts(int* __restrict__ counts) {
    int i = blockIdx.x * 256 + threadIdx.x;
    if (i < N_NODES) counts[i] = 0;
}

__global__ void k_hist(const int* __restrict__ dst, int* __restrict__ counts) {
    int e = blockIdx.x * 256 + threadIdx.x;
    if (e < N_EDGES) atomicAdd(&counts[dst[e]], 1);
}

__global__ void k_blocksum(const int* __restrict__ counts, int* __restrict__ bsum) {
    __shared__ int s[SCAN_B];
    int idx = blockIdx.x * SCAN_B + threadIdx.x;
    int v = (idx < N_NODES) ? counts[idx] : 0;
    s[threadIdx.x] = v;
    __syncthreads();
    for (int off = SCAN_B / 2; off > 0; off >>= 1) {
        if (threadIdx.x < off) s[threadIdx.x] += s[threadIdx.x + off];
        __syncthreads();
    }
    if (threadIdx.x == 0) bsum[blockIdx.x] = s[0];
}

__global__ void k_scan_bsums(int* __restrict__ bsum, int* __restrict__ offsets) {
    if (threadIdx.x == 0 && blockIdx.x == 0) {
        int run = 0;
        for (int i = 0; i < NB; i++) { int t = bsum[i]; bsum[i] = run; run += t; }
        offsets[N_NODES] = N_EDGES;
    }
}

__global__ void k_offsets(const int* __restrict__ counts, const int* __restrict__ bsum,
                          int* __restrict__ offsets, int* __restrict__ cursor) {
    __shared__ int s[SCAN_B];
    int idx = blockIdx.x * SCAN_B + threadIdx.x;
    int v = (idx < N_NODES) ? counts[idx] : 0;
    s[threadIdx.x] = v;
    __syncthreads();
    for (int off = 1; off < SCAN_B; off <<= 1) {
        int t = 0;
        if ((int)threadIdx.x >= off) t = s[threadIdx.x - off];
        __syncthreads();
        s[threadIdx.x] += t;
        __syncthreads();
    }
    if (idx < N_NODES) {
        int excl = s[threadIdx.x] - v;
        int o = bsum[blockIdx.x] + excl;
        offsets[idx] = o;
        cursor[idx]  = o;
    }
}

__global__ void k_scatter(const int* __restrict__ src, const int* __restrict__ dst,
                          int* __restrict__ cursor, int* __restrict__ csr_src) {
    int e = blockIdx.x * 256 + threadIdx.x;
    if (e < N_EDGES) {
        int d = dst[e];
        int p = atomicAdd(&cursor[d], 1);
        csr_src[p] = src[e];
    }
}

// ---------------- weight pack: f32 [K][N] -> hi/lo bf16 in B-fragment order ----------------

__global__ void k_pack(const float* __restrict__ W, int K, int N,
                       unsigned short* __restrict__ hi, unsigned short* __restrict__ lo) {
    int KT = K >> 5, NT = N >> 4;
    int t = blockIdx.x * 256 + threadIdx.x;
    if (t >= KT * NT * 64) return;
    int l = t & 63, tile = t >> 6;
    int kt = tile % KT, nt = tile / KT;
    int n  = nt * 16 + (l & 15);
    int k0 = kt * 32 + (l >> 4) * 8;
    int base = ((nt * KT + kt) * 64 + l) * 8;
    for (int j = 0; j < 8; j++) {
        float w = W[(size_t)(k0 + j) * N + n];
        unsigned short h = f2bf(w);
        hi[base + j] = h;
        lo[base + j] = f2bf(w - bf2f(h));
    }
}

// ---------------- h0 = tanh(gat @ W_in + b_in), MFMA ----------------

__global__ __launch_bounds__(256, 3) void k_h0_mfma(
    const float* __restrict__ gat,
    const unsigned short* __restrict__ wh, const unsigned short* __restrict__ wl,
    const float* __restrict__ b_in, float* __restrict__ h,
    unsigned short* __restrict__ hbf) {
    __shared__ unsigned short Ahi[32][136];
    __shared__ unsigned short Alo[32][136];
    int tid = threadIdx.x;
    int node0 = blockIdx.x * 32;

    for (int idx = tid; idx < 32 * 64; idx += 256) {
        int m = idx >> 6, c = (idx & 63) * 2;
        float2 v;
        if (node0 + m < N_NODES) v = *(const float2*)&gat[(size_t)(node0 + m) * 128 + c];
        else { v.x = 0.f; v.y = 0.f; }
        unsigned short h0 = f2bf(v.x), h1 = f2bf(v.y);
        unsigned short l0 = f2bf(v.x - bf2f(h0)), l1 = f2bf(v.y - bf2f(h1));
        *(unsigned int*)&Ahi[m][c] = (unsigned int)h0 | ((unsigned int)h1 << 16);
        *(unsigned int*)&Alo[m][c] = (unsigned int)l0 | ((unsigned int)l1 << 16);
    }
    __syncthreads();

    int l = tid & 63, wv = tid >> 6;
    int c15 = l & 15, q = l >> 4;
    f32x4 acc[2][2] = {};
#pragma unroll
    for (int kt = 0; kt < 4; kt++) {
        bf16x8 ah[2], al[2];
#pragma unroll
        for (int mt = 0; mt < 2; mt++) {
            ah[mt] = *(const bf16x8*)&Ahi[mt * 16 + c15][kt * 32 + q * 8];
            al[mt] = *(const bf16x8*)&Alo[mt * 16 + c15][kt * 32 + q * 8];
        }
#pragma unroll
        for (int nn = 0; nn < 2; nn++) {
            int nt = wv * 2 + nn;
            bf16x8 bh = *(const bf16x8*)&wh[(size_t)((nt * 4 + kt) * 64 + l) * 8];
            bf16x8 bl = *(const bf16x8*)&wl[(size_t)((nt * 4 + kt) * 64 + l) * 8];
#pragma unroll
            for (int mt = 0; mt < 2; mt++) {
                acc[mt][nn] = __builtin_amdgcn_mfma_f32_16x16x32_bf16(ah[mt], bh, acc[mt][nn], 0, 0, 0);
                acc[mt][nn] = __builtin_amdgcn_mfma_f32_16x16x32_bf16(ah[mt], bl, acc[mt][nn], 0, 0, 0);
                acc[mt][nn] = __builtin_amdgcn_mfma_f32_16x16x32_bf16(al[mt], bh, acc[mt][nn], 0, 0, 0);
            }
        }
    }
#pragma unroll
    for (int nn = 0; nn < 2; nn++) {
        int col = (wv * 2 + nn) * 16 + c15;
        float bb = b_in[col];
#pragma unroll
        for (int mt = 0; mt < 2; mt++)
#pragma unroll
            for (int r = 0; r < 4; r++) {
                int node = node0 + mt * 16 + q * 4 + r;
                if (node < N_NODES) {
                    float v = tanhf(acc[mt][nn][r] + bb);
                    h[(size_t)node * 128 + col]   = v;
                    hbf[(size_t)node * 128 + col] = f2bf(v);
                }
            }
    }
}

// ---------------- fused step, 512 threads / 8 waves, M=32 ----------------
// Round-7 post-mortem: 4-wave fused block = 16 waves/CU, latency-bound in both
// phases. 8 waves halve per-wave gather serialization (4 nodes each) and halve
// per-wave GEMM load chains (2 nt GEMM1 / 1 nt GEMM2), targeting 32 waves/CU.

__global__ __launch_bounds__(512, 4) void k_step(
    const unsigned short* __restrict__ hbf_in,
    float* __restrict__ h, unsigned short* __restrict__ hbf_out,
    const int* __restrict__ offsets, const int* __restrict__ csr,
    const unsigned short* __restrict__ w1h, const unsigned short* __restrict__ w1l,
    const float* __restrict__ b1,
    const unsigned short* __restrict__ w2h, const unsigned short* __restrict__ w2l,
    const float* __restrict__ b2, const float* __restrict__ clr) {
    __shared__ unsigned short Ahi[32][136];
    __shared__ unsigned short Alo[32][136];
    __shared__ unsigned short Y[32][264];
    int tid = threadIdx.x, l = tid & 63, wv = tid >> 6;   // wv 0..7
    int c15 = l & 15, q = l >> 4;
    int node0 = blockIdx.x * 32;
    int g  = l >> 4;       // edge group 0..3
    int cl = l & 15;       // col chunk: cols cl*8..+8

    // ---- Phase 1: segment-mean gather into LDS hi/lo planes (4 nodes/wave) ----
#pragma unroll 1
    for (int i = 0; i < 4; i++) {
        int m = wv * 4 + i;
        int node = node0 + m;
        float a0 = 0.f, a1 = 0.f, a2 = 0.f, a3 = 0.f;
        float a4 = 0.f, a5 = 0.f, a6 = 0.f, a7 = 0.f;
        int deg = 0;
        if (node < N_NODES) {
            int beg = offsets[node], end = offsets[node + 1];
            deg = end - beg;
            int e = beg + g;
            for (; e + 12 < end; e += 16) {
                int i0 = csr[e], i1 = csr[e + 4], i2 = csr[e + 8], i3 = csr[e + 12];
                uint4 w0 = *(const uint4*)&hbf_in[(size_t)i0 * 128 + cl * 8];
                uint4 w1 = *(const uint4*)&hbf_in[(size_t)i1 * 128 + cl * 8];
                uint4 w2 = *(const uint4*)&hbf_in[(size_t)i2 * 128 + cl * 8];
                uint4 w3 = *(const uint4*)&hbf_in[(size_t)i3 * 128 + cl * 8];
                a0 += u2f(w0.x << 16); a1 += u2f(w0.x & 0xFFFF0000u);
                a2 += u2f(w0.y << 16); a3 += u2f(w0.y & 0xFFFF0000u);
                a4 += u2f(w0.z << 16); a5 += u2f(w0.z & 0xFFFF0000u);
                a6 += u2f(w0.w << 16); a7 += u2f(w0.w & 0xFFFF0000u);
                a0 += u2f(w1.x << 16); a1 += u2f(w1.x & 0xFFFF0000u);
                a2 += u2f(w1.y << 16); a3 += u2f(w1.y & 0xFFFF0000u);
                a4 += u2f(w1.z << 16); a5 += u2f(w1.z & 0xFFFF0000u);
                a6 += u2f(w1.w << 16); a7 += u2f(w1.w & 0xFFFF0000u);
                a0 += u2f(w2.x << 16); a1 += u2f(w2.x & 0xFFFF0000u);
                a2 += u2f(w2.y << 16); a3 += u2f(w2.y & 0xFFFF0000u);
                a4 += u2f(w2.z << 16); a5 += u2f(w2.z & 0xFFFF0000u);
                a6 += u2f(w2.w << 16); a7 += u2f(w2.w & 0xFFFF0000u);
                a0 += u2f(w3.x << 16); a1 += u2f(w3.x & 0xFFFF0000u);
                a2 += u2f(w3.y << 16); a3 += u2f(w3.y & 0xFFFF0000u);
                a4 += u2f(w3.z << 16); a5 += u2f(w3.z & 0xFFFF0000u);
                a6 += u2f(w3.w << 16); a7 += u2f(w3.w & 0xFFFF0000u);
            }
            for (; e < end; e += 4) {
                int i0 = csr[e];
                uint4 w0 = *(const uint4*)&hbf_in[(size_t)i0 * 128 + cl * 8];
                a0 += u2f(w0.x << 16); a1 += u2f(w0.x & 0xFFFF0000u);
                a2 += u2f(w0.y << 16); a3 += u2f(w0.y & 0xFFFF0000u);
                a4 += u2f(w0.z << 16); a5 += u2f(w0.z & 0xFFFF0000u);
                a6 += u2f(w0.w << 16); a7 += u2f(w0.w & 0xFFFF0000u);
            }
        }
        a0 += __shfl_xor(a0, 16); a1 += __shfl_xor(a1, 16);
        a2 += __shfl_xor(a2, 16); a3 += __shfl_xor(a3, 16);
        a4 += __shfl_xor(a4, 16); a5 += __shfl_xor(a5, 16);
        a6 += __shfl_xor(a6, 16); a7 += __shfl_xor(a7, 16);
        a0 += __shfl_xor(a0, 32); a1 += __shfl_xor(a1, 32);
        a2 += __shfl_xor(a2, 32); a3 += __shfl_xor(a3, 32);
        a4 += __shfl_xor(a4, 32); a5 += __shfl_xor(a5, 32);
        a6 += __shfl_xor(a6, 32); a7 += __shfl_xor(a7, 32);

        float inv = (deg > 1) ? 1.0f / (float)deg : 1.0f;
        float x0 = a0 * inv, x1 = a1 * inv, x2 = a2 * inv, x3 = a3 * inv;
        float x4 = a4 * inv, x5 = a5 * inv, x6 = a6 * inv, x7 = a7 * inv;
        unsigned short h0 = f2bf(x0), h1 = f2bf(x1), h2 = f2bf(x2), h3 = f2bf(x3);
        unsigned short h4 = f2bf(x4), h5 = f2bf(x5), h6 = f2bf(x6), h7 = f2bf(x7);
        if (g == 0) {
            uint4 o;
            o.x = (unsigned int)h0 | ((unsigned int)h1 << 16);
            o.y = (unsigned int)h2 | ((unsigned int)h3 << 16);
            o.z = (unsigned int)h4 | ((unsigned int)h5 << 16);
            o.w = (unsigned int)h6 | ((unsigned int)h7 << 16);
            *(uint4*)&Ahi[m][cl * 8] = o;
        } else if (g == 1) {
            unsigned short l0 = f2bf(x0 - bf2f(h0)), l1 = f2bf(x1 - bf2f(h1));
            unsigned short l2 = f2bf(x2 - bf2f(h2)), l3 = f2bf(x3 - bf2f(h3));
            unsigned short l4 = f2bf(x4 - bf2f(h4)), l5 = f2bf(x5 - bf2f(h5));
            unsigned short l6 = f2bf(x6 - bf2f(h6)), l7 = f2bf(x7 - bf2f(h7));
            uint4 o;
            o.x = (unsigned int)l0 | ((unsigned int)l1 << 16);
            o.y = (unsigned int)l2 | ((unsigned int)l3 << 16);
            o.z = (unsigned int)l4 | ((unsigned int)l5 << 16);
            o.w = (unsigned int)l6 | ((unsigned int)l7 << 16);
            *(uint4*)&Alo[m][cl * 8] = o;
        }
    }
    __syncthreads();

    // ---- Phase 2: GEMM1 [32x128]@[128x256], 3-product, 2 nt/wave ----
    {
        f32x4 acc1[2][2] = {};   // [mt][nn]
#pragma unroll
        for (int kt = 0; kt < 4; kt++) {
            bf16x8 ah[2], al[2];
#pragma unroll
            for (int mt = 0; mt < 2; mt++) {
                ah[mt] = *(const bf16x8*)&Ahi[mt * 16 + c15][kt * 32 + q * 8];
                al[mt] = *(const bf16x8*)&Alo[mt * 16 + c15][kt * 32 + q * 8];
            }
#pragma unroll
            for (int nn = 0; nn < 2; nn++) {
                int nt = wv * 2 + nn;
                bf16x8 bh = *(const bf16x8*)&w1h[(size_t)((nt * 4 + kt) * 64 + l) * 8];
                bf16x8 bl = *(const bf16x8*)&w1l[(size_t)((nt * 4 + kt) * 64 + l) * 8];
#pragma unroll
                for (int mt = 0; mt < 2; mt++) {
                    acc1[mt][nn] = __builtin_amdgcn_mfma_f32_16x16x32_bf16(ah[mt], bh, acc1[mt][nn], 0, 0, 0);
                    acc1[mt][nn] = __builtin_amdgcn_mfma_f32_16x16x32_bf16(ah[mt], bl, acc1[mt][nn], 0, 0, 0);
                    acc1[mt][nn] = __builtin_amdgcn_mfma_f32_16x16x32_bf16(al[mt], bh, acc1[mt][nn], 0, 0, 0);
                }
            }
        }
#pragma unroll
        for (int nn = 0; nn < 2; nn++) {
            int col = (wv * 2 + nn) * 16 + c15;
            float bb = b1[col];
#pragma unroll
            for (int mt = 0; mt < 2; mt++)
#pragma unroll
                for (int r = 0; r < 4; r++) {
                    int row = mt * 16 + q * 4 + r;
                    float x = acc1[mt][nn][r] + bb;
                    float gg = 0.5f * x * (1.0f + erff(x * 0.70710678118654752f));
                    Y[row][col] = f2bf(gg);
                }
        }
    }
    __syncthreads();

    // ---- Phase 3: GEMM2 [32x256]@[256x128], 2-product, 1 nt/wave ----
    f32x4 acc2[2] = {};   // [mt]
#pragma unroll
    for (int kt = 0; kt < 8; kt++) {
        bf16x8 ya[2];
#pragma unroll
        for (int mt = 0; mt < 2; mt++)
            ya[mt] = *(const bf16x8*)&Y[mt * 16 + c15][kt * 32 + q * 8];
        bf16x8 bh = *(const bf16x8*)&w2h[(size_t)((wv * 8 + kt) * 64 + l) * 8];
        bf16x8 bl = *(const bf16x8*)&w2l[(size_t)((wv * 8 + kt) * 64 + l) * 8];
#pragma unroll
        for (int mt = 0; mt < 2; mt++) {
            acc2[mt] = __builtin_amdgcn_mfma_f32_16x16x32_bf16(ya[mt], bh, acc2[mt], 0, 0, 0);
            acc2[mt] = __builtin_amdgcn_mfma_f32_16x16x32_bf16(ya[mt], bl, acc2[mt], 0, 0, 0);
        }
    }
    float decay = fmaxf(clr[0], 0.0f);
    {
        int col = wv * 16 + c15;
        float bb = b2[col];
#pragma unroll
        for (int mt = 0; mt < 2; mt++)
#pragma unroll
            for (int r = 0; r < 4; r++) {
                int node = node0 + mt * 16 + q * 4 + r;
                if (node < N_NODES) {
                    float hv = h[(size_t)node * 128 + col];
                    float diff = tanhf(acc2[mt][r] + bb);
                    float nh = hv + (diff - decay * hv) * DT;
                    h[(size_t)node * 128 + col]       = nh;
                    hbf_out[(size_t)node * 128 + col] = f2bf(nh);
                }
            }
    }
}

// ---------------- launch ----------------

extern "C" void kernel_launch(void* const* d_in, const int* in_sizes, int n_in,
                              void* d_out, int out_size, void* d_ws, size_t ws_size,
                              hipStream_t stream) {
    const float* gat   = (const float*)d_in[0];
    const int*   edges = (const int*)d_in[1];     // [2, E]: row0 = src, row1 = dst
    const float* W_in  = (const float*)d_in[2];
    const float* b_in  = (const float*)d_in[3];
    const float* W1    = (const float*)d_in[4];
    const float* b1    = (const float*)d_in[5];
    const float* W2    = (const float*)d_in[6];
    const float* b2    = (const float*)d_in[7];
    const float* clr   = (const float*)d_in[8];
    float* h = (float*)d_out;

    const int* src = edges;
    const int* dst = edges + N_EDGES;

    char* ws = (char*)d_ws;
    size_t off = 0;
    auto alloc = [&](size_t bytes) -> void* {
        off = (off + 255) & ~(size_t)255;
        void* p = ws + off;
        off += bytes;
        return p;
    };
    int*   counts  = (int*)alloc(sizeof(int) * N_NODES);
    int*   offsets = (int*)alloc(sizeof(int) * (N_NODES + 1));
    int*   cursor  = (int*)alloc(sizeof(int) * N_NODES);
    int*   bsum    = (int*)alloc(sizeof(int) * NB);
    int*   csr_src = (int*)alloc(sizeof(int) * N_EDGES);
    unsigned short* hbfA = (unsigned short*)alloc(sizeof(short) * (size_t)N_PAD * HID);
    unsigned short* hbfB = (unsigned short*)alloc(sizeof(short) * (size_t)N_PAD * HID);
    unsigned short* w1h  = (unsigned short*)alloc(sizeof(short) * HID * H2);
    unsigned short* w1l  = (unsigned short*)alloc(sizeof(short) * HID * H2);
    unsigned short* w2h  = (unsigned short*)alloc(sizeof(short) * H2 * HID);
    unsigned short* w2l  = (unsigned short*)alloc(sizeof(short) * H2 * HID);
    unsigned short* winh = (unsigned short*)alloc(sizeof(short) * HID * HID);
    unsigned short* winl = (unsigned short*)alloc(sizeof(short) * HID * HID);

    // weight packing (once per call)
    k_pack<<<16, 256, 0, stream>>>(W1, 128, 256, w1h, w1l);
    k_pack<<<16, 256, 0, stream>>>(W2, 256, 128, w2h, w2l);
    k_pack<<<8, 256, 0, stream>>>(W_in, 128, 128, winh, winl);

    // CSR build
    k_zero_counts<<<NB, 256, 0, stream>>>(counts);
    k_hist<<<(N_EDGES + 255) / 256, 256, 0, stream>>>(dst, counts);
    k_blocksum<<<NB, 256, 0, stream>>>(counts, bsum);
    k_scan_bsums<<<1, 64, 0, stream>>>(bsum, offsets);
    k_offsets<<<NB, 256, 0, stream>>>(counts, bsum, offsets, cursor);
    k_scatter<<<(N_EDGES + 255) / 256, 256, 0, stream>>>(src, dst, cursor, csr_src);

    // h0 (writes f32 h and bf16 hbfA)
    k_h0_mfma<<<NODE_BLOCKS, 256, 0, stream>>>(gat, winh, winl, b_in, h, hbfA);

    // 12 fused Euler steps; bf16 state ping-pongs, f32 h in place
    for (int s = 0; s < STEPS; s++) {
        const unsigned short* in = (s & 1) ? hbfB : hbfA;
        unsigned short*      out = (s & 1) ? hbfA : hbfB;
        k_step<<<NODE_BLOCKS, 512, 0, stream>>>(in, h, out, offsets, csr_src,
                                                w1h, w1l, b1, w2h, w2l, b2, clr);
    }
}